// Round 1
// 475.186 us; speedup vs baseline: 1.2083x; 1.2083x over previous
//
#include <hip/hip_runtime.h>

typedef __attribute__((ext_vector_type(8))) __bf16 bf16x8;
typedef __attribute__((ext_vector_type(4))) float f32x4;
typedef __attribute__((ext_vector_type(8))) unsigned short u16x8;
typedef __attribute__((ext_vector_type(4))) unsigned short u16x4;

#define B_SZ 512
#define N_SZ 256
#define H_SZ 128

__device__ __forceinline__ float bf2f(unsigned short u) {
    unsigned int x = ((unsigned int)u) << 16;
    return __builtin_bit_cast(float, x);
}
__device__ __forceinline__ unsigned short f2bf(float f) {
    unsigned int x = __builtin_bit_cast(unsigned int, f);
    x += 0x7FFFu + ((x >> 16) & 1u);
    return (unsigned short)(x >> 16);
}

// ---------------------------------------------------------------------------
// K0: detect idx element width. int64 (values < 50000) -> all odd int32 words
// zero. int32 real data -> some odd word nonzero. flag=1 -> int32.
// 64 blocks, int4 vector loads; flag pre-zeroed by hipMemsetAsync.
// Coverage identical to old version: odd words of the first 512 KB.
// ---------------------------------------------------------------------------
__global__ __launch_bounds__(256) void detect_kernel(const int4* __restrict__ idx4,
                                                     int* __restrict__ flag) {
    int t = blockIdx.x * 256 + threadIdx.x;
    int any = 0;
#pragma unroll
    for (int r = 0; r < 2; r++) {
        int4 v = idx4[t + r * 16384];  // 32768 int4 = 512 KB
        any |= (v.y | v.w);
    }
    if (any) atomicOr(flag, 1);
}

// ---------------------------------------------------------------------------
// K1: A (f32 [512,256,512]) -> A2 = A[:,:,:256] + A[:,:,256:] (bf16)
//     plus d[row] = 1/sqrt(rowsum(A2) + 1)  (fp32)
// one wave per row, lane covers j = lane*4 .. lane*4+3 from both halves
// ---------------------------------------------------------------------------
__global__ __launch_bounds__(256) void rowsum_kernel(const float* __restrict__ A,
                                                     unsigned short* __restrict__ A2,
                                                     float* __restrict__ d) {
    int row = blockIdx.x * 4 + (threadIdx.x >> 6);
    int lane = threadIdx.x & 63;
    const float* p = A + (size_t)row * 512 + lane * 4;
    f32x4 vin = *(const f32x4*)p;
    f32x4 vout = *(const f32x4*)(p + 256);
    f32x4 a2 = vin + vout;
    float s = a2[0] + a2[1] + a2[2] + a2[3];
    u16x4 pk;
#pragma unroll
    for (int e = 0; e < 4; e++) pk[e] = f2bf(a2[e]);
    *(u16x4*)(A2 + (size_t)row * 256 + lane * 4) = pk;
#pragma unroll
    for (int m = 32; m >= 1; m >>= 1) s += __shfl_xor(s, m, 64);
    if (lane == 0) d[row] = 1.0f / sqrtf(s + 1.0f);  // rowsum >= 1, never inf
}

// ---------------------------------------------------------------------------
// K2 (in place): A2[b,i,j] <- 0.8*norm + (i==j ? 0.1*(1-norm) : 0)
//     norm = (A2 + (i==j)) * d_i * d_j
// ---------------------------------------------------------------------------
__global__ __launch_bounds__(256) void mix_kernel(unsigned short* __restrict__ A2,
                                                  const float* __restrict__ d) {
    int tid = threadIdx.x;
    int row = blockIdx.x * 8 + (tid >> 5);  // global row = b*256 + i
    int b = row >> 8;
    int i = row & 255;
    int jb = (tid & 31) * 8;
    unsigned short* Ar = A2 + (size_t)row * 256 + jb;
    u16x8 v = *(const u16x8*)Ar;
    float di = d[row];
    const float* dj = d + b * 256 + jb;
    u16x8 res;
#pragma unroll
    for (int e = 0; e < 8; e++) {
        float a = bf2f(v[e]);
        bool diag = (i == jb + e);
        if (diag) a += 1.0f;
        float na = a * di * dj[e];
        float val = 0.8f * na;
        if (diag) val += 0.1f * (1.0f - na);
        res[e] = f2bf(val);
    }
    *(u16x8*)Ar = res;
}

// ---------------------------------------------------------------------------
// K3: gather + transpose: outT[b, h, j] = bf16(emb[idx[b,j], h]), emb f32
// Each lane reads a CONTIGUOUS 128B slice of one emb row (sub0*16..+32 h):
// full 64B-line consumption vs old 2x16B scatter. LDS transpose unchanged:
// write lanes span jj -> conflict-free; read phase identical to old kernel.
// ---------------------------------------------------------------------------
__global__ __launch_bounds__(256) void gather_kernel(const int* __restrict__ idx,
                                                     const float* __restrict__ emb,
                                                     const int* __restrict__ flag,
                                                     unsigned short* __restrict__ outT) {
    __shared__ unsigned short tileT[128 * 72];  // [h][jj], stride 72
    int b = blockIdx.y;
    int j0 = blockIdx.x * 64;
    int tid = threadIdx.x;
    int jj = tid & 63;
    int sub0 = (tid >> 6) * 2;  // 0,2,4,6 -> each thread does sub0, sub0+1
    int pos = b * 256 + j0 + jj;
    int node = (flag[0] != 0) ? idx[pos] : idx[2 * pos];  // int64: low word
    const float* erow = emb + (size_t)node * 128;
#pragma unroll
    for (int s2 = 0; s2 < 2; s2++) {
        int h0 = (sub0 + s2) * 16;
        f32x4 v0 = *(const f32x4*)(erow + h0);
        f32x4 v1 = *(const f32x4*)(erow + h0 + 4);
        f32x4 v2 = *(const f32x4*)(erow + h0 + 8);
        f32x4 v3 = *(const f32x4*)(erow + h0 + 12);
#pragma unroll
        for (int e = 0; e < 4; e++) {
            tileT[(h0 + e) * 72 + jj] = f2bf(v0[e]);
            tileT[(h0 + 4 + e) * 72 + jj] = f2bf(v1[e]);
            tileT[(h0 + 8 + e) * 72 + jj] = f2bf(v2[e]);
            tileT[(h0 + 12 + e) * 72 + jj] = f2bf(v3[e]);
        }
    }
    __syncthreads();
#pragma unroll
    for (int p = 0; p < 4; p++) {
        int h = (tid >> 3) + p * 32;
        int jc = (tid & 7) * 8;
        u16x8 v = *(const u16x8*)(&tileT[h * 72 + jc]);
        *(u16x8*)(outT + ((size_t)b * 128 + h) * 256 + j0 + jc) = v;
    }
}

// ---------------------------------------------------------------------------
// K4: fused 2-hop propagation. One block per batch (512 thr = 8 waves,
// wave tile 64x64, waves 4(m) x 2(n)). B-panel (128 h x 256 k bf16 = 64KB)
// resident in LDS, XOR-swizzled (byte ^= (h&7)<<4) so the stride-512B row
// reads are bank-conflict-free. A-fragments are read straight from global:
// one 16x16x32 fragment load = 16 full 64B lines, and the block's 128KB
// A-slice is L2-resident for hop 2. K-loop has ZERO barriers.
// hop1: acc = Amix @ h0 (panel);  h1 -> bf16 -> panel (2 barriers);
// hop2: acc = Amix @ h1 (panel);  epilogue writes fp32 out[b,i,h].
// ---------------------------------------------------------------------------
__global__ __launch_bounds__(512) void gemm_fused(const unsigned short* __restrict__ Amix,
                                                  const unsigned short* __restrict__ HT,
                                                  float* __restrict__ outF) {
    __shared__ __align__(16) unsigned char Bs[65536];
    int b = blockIdx.x;
    int tid = threadIdx.x;
    int lane = tid & 63;
    int w = tid >> 6;
    int q = lane >> 4, ln = lane & 15;
    int wm = w >> 1, wn = w & 1;

    const unsigned short* Hb = HT + (size_t)b * 128 * 256;
    const unsigned short* Ab = Amix + (size_t)b * 256 * 256;

    // stage h0 panel into Bs (swizzled). 4096 16B chunks / 512 threads.
#pragma unroll
    for (int r = 0; r < 8; r++) {
        int c = tid + r * 512;
        int h = c >> 5;
        int koff = (c & 31) << 4;  // byte offset within row (< 512)
        u16x8 v = *(const u16x8*)(Hb + h * 256 + (c & 31) * 8);
        int byte = ((h << 9) + koff) ^ ((h & 7) << 4);
        *(u16x8*)(Bs + byte) = v;
    }

    int arow[4], bb[4], bsw[4];
#pragma unroll
    for (int mt = 0; mt < 4; mt++) arow[mt] = wm * 64 + mt * 16 + ln;
#pragma unroll
    for (int nt = 0; nt < 4; nt++) {
        int h = wn * 64 + nt * 16 + ln;
        bb[nt] = h << 9;
        bsw[nt] = (h & 7) << 4;
    }

    f32x4 acc[4][4];
#pragma unroll
    for (int mt = 0; mt < 4; mt++)
#pragma unroll
        for (int nt = 0; nt < 4; nt++) acc[mt][nt] = f32x4{0.f, 0.f, 0.f, 0.f};

    __syncthreads();  // h0 panel visible

    // ---- hop 1 ----
#pragma unroll
    for (int s = 0; s < 8; s++) {
        int k0 = s * 32;
        bf16x8 af[4], bf[4];
#pragma unroll
        for (int mt = 0; mt < 4; mt++)
            af[mt] = *(const bf16x8*)(Ab + arow[mt] * 256 + k0 + q * 8);
#pragma unroll
        for (int nt = 0; nt < 4; nt++)
            bf[nt] = *(const bf16x8*)(Bs + ((bb[nt] + k0 * 2 + q * 16) ^ bsw[nt]));
#pragma unroll
        for (int mt = 0; mt < 4; mt++)
#pragma unroll
            for (int nt = 0; nt < 4; nt++)
                acc[mt][nt] = __builtin_amdgcn_mfma_f32_16x16x32_bf16(af[mt], bf[nt],
                                                                      acc[mt][nt], 0, 0, 0);
    }

    __syncthreads();  // all waves done reading h0 panel

    // write h1 into Bs: layout [h][i], same swizzle.
    // C/D layout: col(h)=ln, row(i)=q*4+reg -> regs are i-consecutive (u16x4).
#pragma unroll
    for (int mt = 0; mt < 4; mt++)
#pragma unroll
        for (int nt = 0; nt < 4; nt++) {
            int h = wn * 64 + nt * 16 + ln;
            int i0 = wm * 64 + mt * 16 + q * 4;
            u16x4 pk;
#pragma unroll
            for (int r = 0; r < 4; r++) pk[r] = f2bf(acc[mt][nt][r]);
            int byte = ((h << 9) + (i0 << 1)) ^ ((h & 7) << 4);
            *(u16x4*)(Bs + byte) = pk;
            acc[mt][nt] = f32x4{0.f, 0.f, 0.f, 0.f};
        }

    __syncthreads();  // h1 panel visible

    // ---- hop 2 ----
#pragma unroll
    for (int s = 0; s < 8; s++) {
        int k0 = s * 32;
        bf16x8 af[4], bf[4];
#pragma unroll
        for (int mt = 0; mt < 4; mt++)
            af[mt] = *(const bf16x8*)(Ab + arow[mt] * 256 + k0 + q * 8);
#pragma unroll
        for (int nt = 0; nt < 4; nt++)
            bf[nt] = *(const bf16x8*)(Bs + ((bb[nt] + k0 * 2 + q * 16) ^ bsw[nt]));
#pragma unroll
        for (int mt = 0; mt < 4; mt++)
#pragma unroll
            for (int nt = 0; nt < 4; nt++)
                acc[mt][nt] = __builtin_amdgcn_mfma_f32_16x16x32_bf16(af[mt], bf[nt],
                                                                      acc[mt][nt], 0, 0, 0);
    }

    // epilogue: out[b, i, h] fp32 (quad lanes q=0..3 give 32B-contiguous runs)
#pragma unroll
    for (int mt = 0; mt < 4; mt++)
#pragma unroll
        for (int nt = 0; nt < 4; nt++) {
            int h = wn * 64 + nt * 16 + ln;
            int i0 = wm * 64 + mt * 16 + q * 4;
#pragma unroll
            for (int r = 0; r < 4; r++)
                outF[((size_t)b * 256 + i0 + r) * 128 + h] = acc[mt][nt][r];
        }
}

extern "C" void kernel_launch(void* const* d_in, const int* in_sizes, int n_in,
                              void* d_out, int out_size, void* d_ws, size_t ws_size,
                              hipStream_t stream) {
    const int* idx = (const int*)d_in[0];      // [512,256] int32 or int64
    const float* A = (const float*)d_in[1];    // [512,256,512] f32
    const float* emb = (const float*)d_in[2];  // [50000,128] f32
    float* out = (float*)d_out;                // [512,256,128] f32

    char* ws = (char*)d_ws;
    int* flag = (int*)ws;                                    // 4 B
    float* d = (float*)(ws + 4096);                          // 512 KB
    unsigned short* A2 = (unsigned short*)(ws + 528384);     // 64 MB (A2 -> Amix in place)
    unsigned short* h0T = (unsigned short*)(ws + 67637248);  // 33.5 MB

    hipMemsetAsync(flag, 0, 4, stream);
    detect_kernel<<<64, 256, 0, stream>>>((const int4*)idx, flag);
    rowsum_kernel<<<B_SZ * N_SZ / 4, 256, 0, stream>>>(A, A2, d);
    mix_kernel<<<B_SZ * N_SZ / 8, 256, 0, stream>>>(A2, d);
    gather_kernel<<<dim3(4, B_SZ), 256, 0, stream>>>(idx, emb, flag, h0T);
    gemm_fused<<<B_SZ, 512, 0, stream>>>(A2, h0T, out);
}

// Round 2
// 440.738 us; speedup vs baseline: 1.3027x; 1.0782x over previous
//
#include <hip/hip_runtime.h>

typedef __attribute__((ext_vector_type(8))) __bf16 bf16x8;
typedef __attribute__((ext_vector_type(4))) float f32x4;
typedef __attribute__((ext_vector_type(8))) unsigned short u16x8;
typedef __attribute__((ext_vector_type(4))) unsigned short u16x4;

#define B_SZ 512

static __device__ __forceinline__ float bf2f(unsigned short u) {
    unsigned int x = ((unsigned int)u) << 16;
    return __builtin_bit_cast(float, x);
}
static __device__ __forceinline__ unsigned short f2bf(float f) {
    unsigned int x = __builtin_bit_cast(unsigned int, f);
    x += 0x7FFFu + ((x >> 16) & 1u);
    return (unsigned short)(x >> 16);
}

// ---------------------------------------------------------------------------
// K0: detect idx element width. int64 (values < 50000) -> all odd int32 words
// zero. int32 real data -> some odd word nonzero. flag=1 -> int32.
// flag pre-zeroed by hipMemsetAsync. Reads exactly the first 512 KB.
// ---------------------------------------------------------------------------
__global__ __launch_bounds__(256) void detect_kernel(const int4* __restrict__ idx4,
                                                     int* __restrict__ flag) {
    int t = blockIdx.x * 256 + threadIdx.x;
    int any = 0;
#pragma unroll
    for (int r = 0; r < 2; r++) {
        int4 v = idx4[t + r * 16384];  // 32768 int4 = 512 KB
        any |= (v.y | v.w);
    }
    if (any) atomicOr(flag, 1);
}

// ---------------------------------------------------------------------------
// K1: whole pipeline, one block per batch. 512 thr = 8 waves, wave w owns
// m-strip rows w*32..w*32+31 x all 128 h (acc 2x8 f32x4 = 64 VGPR).
// LDS map (132096 B):
//   [0      .. 131072) : a2 bf16 [256 r][256 c], row stride 512 B,
//                        XOR-swizzled byte ^= (r&7)<<4  (phases 1-2)
//                        then: [0..65536) h0/h1-src panel [128 h][256 j]
//                              [65536..131072) h1 panel   [128 h][256 i]
//   [131072 .. 132096) : d[256] f32
// Phases: stage(A->a2,d) |bar| frag(a2+mix -> 64 VGPR Amix frags; emb loads
// issued early) |bar| panel write |bar| hop1 -> h1 region |bar| hop2 -> out.
// All LDS b128 access patterns land on 8 distinct 16B slots / 128 B line
// (structural minimum, conflict-free).
// ---------------------------------------------------------------------------
__global__ __launch_bounds__(512) void fused_kernel(const int* __restrict__ idx,
                                                    const float* __restrict__ A,
                                                    const float* __restrict__ emb,
                                                    const int* __restrict__ flag,
                                                    float* __restrict__ outF) {
    __shared__ __align__(16) unsigned char smem[132096];
    float* dL = (float*)(smem + 131072);

    int b = blockIdx.x;
    int tid = threadIdx.x;
    int w = tid >> 6;  // wave id = m-strip
    int lane = tid & 63;
    int q = lane >> 4;
    int ln = lane & 15;

    const float* Ab = A + (size_t)b * 256 * 512;

    // ---- phase 1: A -> a2 (bf16, swizzled LDS) + d = 1/sqrt(rowsum+1) ----
    for (int rr = 0; rr < 32; rr += 4) {
        f32x4 va[4], vb[4];
#pragma unroll
        for (int u = 0; u < 4; u++) {
            const float* p = Ab + (size_t)(w * 32 + rr + u) * 512 + lane * 4;
            va[u] = *(const f32x4*)p;       // cols lane*4..+3
            vb[u] = *(const f32x4*)(p + 256);  // second half
        }
#pragma unroll
        for (int u = 0; u < 4; u++) {
            int row = w * 32 + rr + u;
            f32x4 a2 = va[u] + vb[u];
            u16x4 pk;
#pragma unroll
            for (int e = 0; e < 4; e++) pk[e] = f2bf(a2[e]);
            int byte_ = ((row << 9) + (lane << 3)) ^ ((row & 7) << 4);
            *(u16x4*)(smem + byte_) = pk;
            float s = a2[0] + a2[1] + a2[2] + a2[3];
#pragma unroll
            for (int m = 32; m >= 1; m >>= 1) s += __shfl_xor(s, m, 64);
            if (lane == 0) dL[row] = 1.0f / sqrtf(s + 1.0f);  // rowsum>=1
        }
    }
    __syncthreads();  // a2 + d visible

    // ---- early gather issue (T14): emb row loads in flight across phase 2
    int j = tid & 255;
    int hh = tid >> 8;  // h-half: 0 or 1
    int pos = b * 256 + j;
    int node = (flag[0] != 0) ? idx[pos] : idx[2 * pos];  // int64: low word
    const float* erow = emb + (size_t)node * 128 + hh * 64;
    f32x4 ev[16];
#pragma unroll
    for (int p = 0; p < 16; p++) ev[p] = *(const f32x4*)(erow + p * 4);

    // ---- phase 2: Amix fragments in registers (mix applied on the fly) ----
    // afr[mt][s]: rows w*32+mt*16+ln, k-cols s*32+q*8..+7 (MFMA A layout)
    bf16x8 afr[2][8];
#pragma unroll
    for (int s = 0; s < 8; s++) {
        f32x4 dc0 = *(const f32x4*)(dL + s * 32 + q * 8);
        f32x4 dc1 = *(const f32x4*)(dL + s * 32 + q * 8 + 4);
#pragma unroll
        for (int mt = 0; mt < 2; mt++) {
            int r = w * 32 + mt * 16 + ln;
            int byte_ = ((r << 9) + s * 64 + q * 16) ^ ((r & 7) << 4);
            u16x8 a = *(const u16x8*)(smem + byte_);
            float dr = dL[r];
            u16x8 o;
#pragma unroll
            for (int e = 0; e < 8; e++) {
                int c = s * 32 + q * 8 + e;
                float av = bf2f(a[e]);
                bool diag = (r == c);
                if (diag) av += 1.0f;
                float na = av * dr * ((e < 4) ? dc0[e] : dc1[e - 4]);
                float v = 0.8f * na;
                if (diag) v += 0.1f * (1.0f - na);
                o[e] = f2bf(v);
            }
            afr[mt][s] = __builtin_bit_cast(bf16x8, o);
        }
    }
    __syncthreads();  // all a2 reads done -> region reusable

    // ---- phase 3: h0 panel [h][j] into smem[0..65536), swizzled ----
    // wave covers 64 consecutive j at fixed hh -> 128 B contiguous per write
#pragma unroll
    for (int p = 0; p < 16; p++) {
#pragma unroll
        for (int e = 0; e < 4; e++) {
            int h = hh * 64 + p * 4 + e;
            int byte_ = ((h << 9) + (j << 1)) ^ ((h & 7) << 4);
            *(unsigned short*)(smem + byte_) = f2bf(ev[p][e]);
        }
    }
    __syncthreads();  // h0 panel visible

    f32x4 acc[2][8];
#pragma unroll
    for (int mt = 0; mt < 2; mt++)
#pragma unroll
        for (int nt = 0; nt < 8; nt++) acc[mt][nt] = f32x4{0.f, 0.f, 0.f, 0.f};

    // ---- hop 1: acc = Amix(reg) @ h0(LDS) ----
#pragma unroll
    for (int s = 0; s < 8; s++) {
        bf16x8 bfr[8];
#pragma unroll
        for (int nt = 0; nt < 8; nt++) {
            int h = nt * 16 + ln;
            int byte_ = ((h << 9) + s * 64 + q * 16) ^ ((h & 7) << 4);
            bfr[nt] = *(const bf16x8*)(smem + byte_);
        }
#pragma unroll
        for (int mt = 0; mt < 2; mt++)
#pragma unroll
            for (int nt = 0; nt < 8; nt++)
                acc[mt][nt] = __builtin_amdgcn_mfma_f32_16x16x32_bf16(
                    afr[mt][s], bfr[nt], acc[mt][nt], 0, 0, 0);
    }

    // ---- h1 -> region B [h][i] (disjoint from h0 region: no pre-barrier) ----
    // C/D layout: col(h)=ln, row(i)=q*4+reg -> i-consecutive u16x4
#pragma unroll
    for (int mt = 0; mt < 2; mt++)
#pragma unroll
        for (int nt = 0; nt < 8; nt++) {
            int h = nt * 16 + ln;
            int i0 = w * 32 + mt * 16 + q * 4;
            u16x4 pk;
#pragma unroll
            for (int r = 0; r < 4; r++) pk[r] = f2bf(acc[mt][nt][r]);
            int byte_ = 65536 + (((h << 9) + (i0 << 1)) ^ ((h & 7) << 4));
            *(u16x4*)(smem + byte_) = pk;
            acc[mt][nt] = f32x4{0.f, 0.f, 0.f, 0.f};
        }
    __syncthreads();  // h1 visible

    // ---- hop 2: acc = Amix(reg) @ h1(LDS region B) ----
#pragma unroll
    for (int s = 0; s < 8; s++) {
        bf16x8 bfr[8];
#pragma unroll
        for (int nt = 0; nt < 8; nt++) {
            int h = nt * 16 + ln;
            int byte_ = 65536 + (((h << 9) + s * 64 + q * 16) ^ ((h & 7) << 4));
            bfr[nt] = *(const bf16x8*)(smem + byte_);
        }
#pragma unroll
        for (int mt = 0; mt < 2; mt++)
#pragma unroll
            for (int nt = 0; nt < 8; nt++)
                acc[mt][nt] = __builtin_amdgcn_mfma_f32_16x16x32_bf16(
                    afr[mt][s], bfr[nt], acc[mt][nt], 0, 0, 0);
    }

    // ---- epilogue: out[b, i, h] fp32 ----
#pragma unroll
    for (int mt = 0; mt < 2; mt++)
#pragma unroll
        for (int nt = 0; nt < 8; nt++) {
            int h = nt * 16 + ln;
            int i0 = w * 32 + mt * 16 + q * 4;
#pragma unroll
            for (int r = 0; r < 4; r++)
                outF[((size_t)b * 256 + i0 + r) * 128 + h] = acc[mt][nt][r];
        }
}

extern "C" void kernel_launch(void* const* d_in, const int* in_sizes, int n_in,
                              void* d_out, int out_size, void* d_ws, size_t ws_size,
                              hipStream_t stream) {
    const int* idx = (const int*)d_in[0];      // [512,256] int32 or int64
    const float* A = (const float*)d_in[1];    // [512,256,512] f32
    const float* emb = (const float*)d_in[2];  // [50000,128] f32
    float* out = (float*)d_out;                // [512,256,128] f32

    int* flag = (int*)d_ws;

    hipMemsetAsync(flag, 0, 4, stream);
    detect_kernel<<<64, 256, 0, stream>>>((const int4*)idx, flag);
    fused_kernel<<<B_SZ, 512, 0, stream>>>(idx, A, emb, flag, out);
}